// Round 5
// baseline (197.746 us; speedup 1.0000x reference)
//
#include <hip/hip_runtime.h>

#define BS 32
#define NA 512
#define ID 128
#define NH 8
#define HD 64
#define NHD 512   // NH*HD
#define NEG 0.2f
#define NC 32
#define CH 16

// K1: h_prime = h @ W (fp32). Block = 16 rows x 512 cols.
// Wave w: rows (w>>1)*8..+7, cols (w&1)*256 + 4*lane..+3  -> W loads are
// DENSE 1KB/instr (R4: lane*8 gave 50%-density 2KB spans = L1-service-bound)
// and W is read 2x per block instead of 4x.
__global__ __launch_bounds__(256) void k1_gemm(
    const float* __restrict__ h, const float* __restrict__ W,
    const float* __restrict__ att, float* __restrict__ hp,
    float* __restrict__ s_out, float* __restrict__ t_out) {
  __shared__ float hs[ID * 20];  // hs[k*20 + r]
  int blk = blockIdx.x;
  int b = blk >> 5;               // 32 blocks per batch
  int n0 = (blk & 31) * 16;
  int t = threadIdx.x;
  const float* hbase = h + ((size_t)b * NA + n0) * ID;
  {
    int r = t & 15;
    int k0 = (t >> 4) * 8;
    const float* src = hbase + r * ID + k0;
    float4 v0 = *(const float4*)(src);
    float4 v1 = *(const float4*)(src + 4);
    hs[(k0 + 0) * 20 + r] = v0.x;
    hs[(k0 + 1) * 20 + r] = v0.y;
    hs[(k0 + 2) * 20 + r] = v0.z;
    hs[(k0 + 3) * 20 + r] = v0.w;
    hs[(k0 + 4) * 20 + r] = v1.x;
    hs[(k0 + 5) * 20 + r] = v1.y;
    hs[(k0 + 6) * 20 + r] = v1.z;
    hs[(k0 + 7) * 20 + r] = v1.w;
  }
  __syncthreads();
  int lane = t & 63, w = t >> 6;
  int r0 = (w >> 1) * 8;          // 0 or 8
  int col = (w & 1) * 256 + lane * 4;
  int head = col >> 6;
  int d0 = col & 63;
  float4 a0c = {0,0,0,0}, a1c = {0,0,0,0}, a2c = {0,0,0,0}, a3c = {0,0,0,0};
  float4 a4c = {0,0,0,0}, a5c = {0,0,0,0}, a6c = {0,0,0,0}, a7c = {0,0,0,0};
  const float* wptr = W + col;
#define K1_FMA(AX, C) C.x += (AX)*wv.x; C.y += (AX)*wv.y; C.z += (AX)*wv.z; C.w += (AX)*wv.w;
  #pragma unroll 4
  for (int k = 0; k < ID; ++k) {
    float4 wv = *(const float4*)(wptr + k * NHD);
    float4 a0 = *(const float4*)(&hs[k * 20 + r0]);
    float4 a1 = *(const float4*)(&hs[k * 20 + r0 + 4]);
    K1_FMA(a0.x, a0c) K1_FMA(a0.y, a1c) K1_FMA(a0.z, a2c) K1_FMA(a0.w, a3c)
    K1_FMA(a1.x, a4c) K1_FMA(a1.y, a5c) K1_FMA(a1.z, a6c) K1_FMA(a1.w, a7c)
  }
#undef K1_FMA
  {
    size_t off = ((((size_t)b * NH + head) * NA) + (n0 + r0)) * HD + d0;
    *(float4*)(hp + off) = a0c; off += HD;
    *(float4*)(hp + off) = a1c; off += HD;
    *(float4*)(hp + off) = a2c; off += HD;
    *(float4*)(hp + off) = a3c; off += HD;
    *(float4*)(hp + off) = a4c; off += HD;
    *(float4*)(hp + off) = a5c; off += HD;
    *(float4*)(hp + off) = a6c; off += HD;
    *(float4*)(hp + off) = a7c;
  }
  // fused s/t: dot acc rows with att_a, reduce over the 16 lanes of this head
  {
    float4 as4 = *(const float4*)(att + head * 128 + d0);
    float4 ad4 = *(const float4*)(att + head * 128 + 64 + d0);
#define DOT4(C, A) ((C).x*(A).x + (C).y*(A).y + (C).z*(A).z + (C).w*(A).w)
    float sp0 = DOT4(a0c, as4), tp0 = DOT4(a0c, ad4);
    float sp1 = DOT4(a1c, as4), tp1 = DOT4(a1c, ad4);
    float sp2 = DOT4(a2c, as4), tp2 = DOT4(a2c, ad4);
    float sp3 = DOT4(a3c, as4), tp3 = DOT4(a3c, ad4);
    float sp4 = DOT4(a4c, as4), tp4 = DOT4(a4c, ad4);
    float sp5 = DOT4(a5c, as4), tp5 = DOT4(a5c, ad4);
    float sp6 = DOT4(a6c, as4), tp6 = DOT4(a6c, ad4);
    float sp7 = DOT4(a7c, as4), tp7 = DOT4(a7c, ad4);
#undef DOT4
    #pragma unroll
    for (int m = 1; m < 16; m <<= 1) {
      sp0 += __shfl_xor(sp0, m, 64); tp0 += __shfl_xor(tp0, m, 64);
      sp1 += __shfl_xor(sp1, m, 64); tp1 += __shfl_xor(tp1, m, 64);
      sp2 += __shfl_xor(sp2, m, 64); tp2 += __shfl_xor(tp2, m, 64);
      sp3 += __shfl_xor(sp3, m, 64); tp3 += __shfl_xor(tp3, m, 64);
      sp4 += __shfl_xor(sp4, m, 64); tp4 += __shfl_xor(tp4, m, 64);
      sp5 += __shfl_xor(sp5, m, 64); tp5 += __shfl_xor(tp5, m, 64);
      sp6 += __shfl_xor(sp6, m, 64); tp6 += __shfl_xor(tp6, m, 64);
      sp7 += __shfl_xor(sp7, m, 64); tp7 += __shfl_xor(tp7, m, 64);
    }
    int g16 = lane & 15;
    int rsel = g16 & 7;
    float sv_ = rsel == 0 ? sp0 : rsel == 1 ? sp1 : rsel == 2 ? sp2 :
                rsel == 3 ? sp3 : rsel == 4 ? sp4 : rsel == 5 ? sp5 :
                rsel == 6 ? sp6 : sp7;
    float tv_ = rsel == 0 ? tp0 : rsel == 1 ? tp1 : rsel == 2 ? tp2 :
                rsel == 3 ? tp3 : rsel == 4 ? tp4 : rsel == 5 ? tp5 :
                rsel == 6 ? tp6 : tp7;
    size_t off = (((size_t)b * NH + head) * NA) + n0 + r0 + rsel;
    if (g16 < 8) s_out[off] = sv_;
    else         t_out[off] = tv_;
  }
}

// K2a: per-(b,h): bitonic sort (t and s), weights, suffix/prefix chunk tables,
// then write tables + per-row {A,B,1/den,js|row<<16} to global ws for k2b.
__global__ __launch_bounds__(512) void k2a_tables(
    const float* __restrict__ hp, const float* __restrict__ s_g,
    const float* __restrict__ t_g, int* __restrict__ tpm_g,
    float2* __restrict__ wpn_g, float* __restrict__ sufP_g,
    float* __restrict__ preN_g, float4* __restrict__ rinfo_g) {
  __shared__ float tv[NA]; __shared__ int tpm[NA];
  __shared__ float sv[NA]; __shared__ int spm[NA];
  __shared__ float wp[NA]; __shared__ float wn[NA];
  __shared__ float rawP[NC * 64]; __shared__ float rawN[NC * 64];
  __shared__ float sufP[(NC + 1) * 64]; __shared__ float preN[(NC + 1) * 64];
  __shared__ float zps[NA + 1]; __shared__ float znp[NA + 1];
  __shared__ float szP[NC]; __shared__ float szN[NC];
  __shared__ float sufZ[NC + 1]; __shared__ float preZ[NC + 1];

  int bh = blockIdx.x;
  int t = threadIdx.x;
  const float* vbase = hp + (size_t)bh * NA * HD;

  tv[t] = t_g[(size_t)bh * NA + t]; tpm[t] = t;
  sv[t] = s_g[(size_t)bh * NA + t]; spm[t] = t;
  __syncthreads();

  for (int size = 2; size <= NA; size <<= 1) {
    for (int stride = size >> 1; stride > 0; stride >>= 1) {
      int i = t, j = i ^ stride;
      if (j > i) {
        bool up = ((i & size) == 0);
        float a = tv[i], b = tv[j];
        if (up ? (a > b) : (a < b)) {
          tv[i] = b; tv[j] = a;
          int x = tpm[i]; tpm[i] = tpm[j]; tpm[j] = x;
        }
        float c = sv[i], d = sv[j];
        if (up ? (c > d) : (c < d)) {
          sv[i] = d; sv[j] = c;
          int x = spm[i]; spm[i] = spm[j]; spm[j] = x;
        }
      }
      __syncthreads();
    }
  }

  float cmax = fmaxf(tv[NA - 1], 0.f);
  float amax = fmaxf(sv[NA - 1], 0.f);
  wp[t] = __expf(tv[t] - cmax);
  wn[t] = __expf(NEG * tv[t] - cmax);
  __syncthreads();

  // chunk vector sums over sorted order (coalesced V reads: lane = dim)
  {
    int d = t & 63, w8 = t >> 6;
    for (int cc = w8; cc < NC; cc += 8) {
      float aP = 0.f, aN = 0.f;
      #pragma unroll
      for (int jj = 0; jj < CH; ++jj) {
        int j = cc * CH + jj;
        float v = vbase[(size_t)tpm[j] * HD + d];
        aP += wp[j] * v;
        aN += wn[j] * v;
      }
      rawP[cc * 64 + d] = aP;
      rawN[cc * 64 + d] = aN;
    }
  }
  __syncthreads();

  if (t < 64) {
    int d = t; float run = 0.f;
    sufP[NC * 64 + d] = 0.f;
    for (int cc = NC - 1; cc >= 0; --cc) { run += rawP[cc * 64 + d]; sufP[cc * 64 + d] = run; }
  } else if (t < 128) {
    int d = t - 64; float run = 0.f;
    for (int cc = 0; cc <= NC; ++cc) { preN[cc * 64 + d] = run; if (cc < NC) run += rawN[cc * 64 + d]; }
  } else if (t < 160) {
    int c = t - 128; float a = 0.f;
    for (int j = c * CH; j < c * CH + CH; ++j) a += wp[j];
    szP[c] = a;
  } else if (t < 192) {
    int c = t - 160; float a = 0.f;
    for (int j = c * CH; j < c * CH + CH; ++j) a += wn[j];
    szN[c] = a;
  }
  __syncthreads();

  if (t == 0) {
    float run = 0.f; sufZ[NC] = 0.f;
    for (int cc = NC - 1; cc >= 0; --cc) { run += szP[cc]; sufZ[cc] = run; }
  } else if (t == 1) {
    float run = 0.f;
    for (int cc = 0; cc <= NC; ++cc) { preZ[cc] = run; if (cc < NC) run += szN[cc]; }
  }
  __syncthreads();

  {
    int ch = t >> 4;
    float a = 0.f;
    for (int k = t; k < ch * CH + CH; ++k) a += wp[k];
    zps[t] = a + sufZ[ch + 1];
    float b2 = 0.f;
    for (int k = ch * CH; k < t; ++k) b2 += wn[k];
    znp[t] = preZ[ch] + b2;
    if (t == 0) { zps[NA] = 0.f; znp[NA] = preZ[NC]; }
  }
  __syncthreads();

  // per-row info: t is the s-rank; pack {A, B, 1/den, js|row<<16}
  {
    float sval = sv[t];
    int row = spm[t];
    float A = __expf(sval - amax);
    float B = __expf(NEG * sval - amax);
    float key = -sval;
    int lo = 0, hi = NA;
    while (lo < hi) { int mid = (lo + hi) >> 1; if (tv[mid] < key) lo = mid + 1; else hi = mid; }
    int js = lo;
    float den = A * zps[js] + B * znp[js];
    float4 ri;
    ri.x = A; ri.y = B; ri.z = 1.f / den;
    ri.w = __int_as_float(js | (row << 16));
    rinfo_g[(size_t)bh * NA + t] = ri;
  }
  // table writes
  tpm_g[(size_t)bh * NA + t] = tpm[t];
  { float2 w2; w2.x = wp[t]; w2.y = wn[t]; wpn_g[(size_t)bh * NA + t] = w2; }
  {
    size_t tb = (size_t)bh * ((NC + 1) * 64);
    for (int i = t; i < (NC + 1) * 64; i += 512) {
      sufP_g[tb + i] = sufP[i];
      preN_g[tb + i] = preN[i];
    }
  }
}

// K2b: apply. Barrier-free, LDS-free. Block 256 = 16 s-ranked rows x 16 dim
// quads; grid 8192. Coalesced V reads, full-cacheline stores, high occupancy.
__global__ __launch_bounds__(256) void k2b_apply(
    const float* __restrict__ hp, const int* __restrict__ tpm_g,
    const float2* __restrict__ wpn_g, const float* __restrict__ sufP_g,
    const float* __restrict__ preN_g, const float4* __restrict__ rinfo_g,
    float* __restrict__ out) {
  int blk = blockIdx.x;
  int bh = blk >> 5;
  int rank0 = (blk & 31) * 16;
  int t = threadIdx.x;
  int g = t >> 4;                 // row within block
  int q = t & 15;                 // dim quad
  int d0 = q * 4;
  int rank = rank0 + g;

  float4 ri = rinfo_g[(size_t)bh * NA + rank];
  float A = ri.x, B = ri.y, inv = ri.z;
  int bits = __float_as_int(ri.w);
  int js = bits & 0xFFFF;
  int row = bits >> 16;
  int cs = js >> 4; if (cs > NC - 1) cs = NC - 1;

  size_t tb = (size_t)bh * ((NC + 1) * 64);
  float4 sp = *(const float4*)(sufP_g + tb + (cs + 1) * 64 + d0);
  float4 pn = *(const float4*)(preN_g + tb + cs * 64 + d0);
  float4 num;
  num.x = A * sp.x + B * pn.x;
  num.y = A * sp.y + B * pn.y;
  num.z = A * sp.z + B * pn.z;
  num.w = A * sp.w + B * pn.w;

  const int* tpmb = tpm_g + (size_t)bh * NA;
  const float2* wpnb = wpn_g + (size_t)bh * NA;
  const float* vb = hp + (size_t)bh * NA * HD;
  #pragma unroll
  for (int jj = 0; jj < CH; ++jj) {
    int j = cs * CH + jj;
    int vr = tpmb[j];
    float2 w2 = wpnb[j];
    float coef = (j >= js) ? A * w2.x : B * w2.y;
    float4 v4 = *(const float4*)(vb + (size_t)vr * HD + d0);
    num.x += coef * v4.x;
    num.y += coef * v4.y;
    num.z += coef * v4.z;
    num.w += coef * v4.w;
  }
  float4 ov;
  float x0 = num.x * inv; ov.x = x0 > 0.f ? x0 : __expf(x0) - 1.f;
  float x1 = num.y * inv; ov.y = x1 > 0.f ? x1 : __expf(x1) - 1.f;
  float x2 = num.z * inv; ov.z = x2 > 0.f ? x2 : __expf(x2) - 1.f;
  float x3 = num.w * inv; ov.w = x3 > 0.f ? x3 : __expf(x3) - 1.f;
  *(float4*)(out + ((size_t)bh * NA + row) * HD + d0) = ov;
}

extern "C" void kernel_launch(void* const* d_in, const int* in_sizes, int n_in,
                              void* d_out, int out_size, void* d_ws, size_t ws_size,
                              hipStream_t stream) {
  const float* h  = (const float*)d_in[0];
  const float* W  = (const float*)d_in[1];
  const float* att = (const float*)d_in[2];
  float* out = (float*)d_out;
  // ws layout (floats): hp 8.39M | s 131k | t 131k | tpm 131k | wpn 262k |
  // sufP 540k | preN 540k | rinfo 524k  => ~42.6 MB total
  float* hp    = (float*)d_ws;
  float* s_arr = hp + (size_t)BS * NH * NA * HD;
  float* t_arr = s_arr + (size_t)BS * NH * NA;
  int*   tpm_g = (int*)(t_arr + (size_t)BS * NH * NA);
  float* wpn_f = (float*)(tpm_g + (size_t)BS * NH * NA);
  float* sufPg = wpn_f + (size_t)BS * NH * NA * 2;
  float* preNg = sufPg + (size_t)BS * NH * (NC + 1) * 64;
  float* rinfo = preNg + (size_t)BS * NH * (NC + 1) * 64;

  k1_gemm   <<<dim3(1024), dim3(256), 0, stream>>>(h, W, att, hp, s_arr, t_arr);
  k2a_tables<<<dim3(256),  dim3(512), 0, stream>>>(hp, s_arr, t_arr, tpm_g,
                                                   (float2*)wpn_f, sufPg, preNg,
                                                   (float4*)rinfo);
  k2b_apply <<<dim3(8192), dim3(256), 0, stream>>>(hp, tpm_g, (float2*)wpn_f,
                                                   sufPg, preNg, (float4*)rinfo,
                                                   out);
}

// Round 6
// 154.890 us; speedup vs baseline: 1.2767x; 1.2767x over previous
//
#include <hip/hip_runtime.h>

#define BS 32
#define NA 512
#define ID 128
#define NH 8
#define HD 64
#define NHD 512   // NH*HD
#define NEG 0.2f
#define NC 32
#define CH 16
#define TROWS (NA + 1)   // 513 table rows per bh (row NA handles js==512)

// K1: h_prime = h @ W (fp32). Block = 16 rows x 512 cols. Wave w: rows
// (w>>1)*8..+7, cols (w&1)*256 + 4*lane -> dense 1KB/instr W loads.
__global__ __launch_bounds__(256) void k1_gemm(
    const float* __restrict__ h, const float* __restrict__ W,
    const float* __restrict__ att, float* __restrict__ hp,
    float* __restrict__ s_out, float* __restrict__ t_out) {
  __shared__ float hs[ID * 20];  // hs[k*20 + r]
  int blk = blockIdx.x;
  int b = blk >> 5;
  int n0 = (blk & 31) * 16;
  int t = threadIdx.x;
  const float* hbase = h + ((size_t)b * NA + n0) * ID;
  {
    int r = t & 15;
    int k0 = (t >> 4) * 8;
    const float* src = hbase + r * ID + k0;
    float4 v0 = *(const float4*)(src);
    float4 v1 = *(const float4*)(src + 4);
    hs[(k0 + 0) * 20 + r] = v0.x;
    hs[(k0 + 1) * 20 + r] = v0.y;
    hs[(k0 + 2) * 20 + r] = v0.z;
    hs[(k0 + 3) * 20 + r] = v0.w;
    hs[(k0 + 4) * 20 + r] = v1.x;
    hs[(k0 + 5) * 20 + r] = v1.y;
    hs[(k0 + 6) * 20 + r] = v1.z;
    hs[(k0 + 7) * 20 + r] = v1.w;
  }
  __syncthreads();
  int lane = t & 63, w = t >> 6;
  int r0 = (w >> 1) * 8;
  int col = (w & 1) * 256 + lane * 4;
  int head = col >> 6;
  int d0 = col & 63;
  float4 a0c = {0,0,0,0}, a1c = {0,0,0,0}, a2c = {0,0,0,0}, a3c = {0,0,0,0};
  float4 a4c = {0,0,0,0}, a5c = {0,0,0,0}, a6c = {0,0,0,0}, a7c = {0,0,0,0};
  const float* wptr = W + col;
#define K1_FMA(AX, C) C.x += (AX)*wv.x; C.y += (AX)*wv.y; C.z += (AX)*wv.z; C.w += (AX)*wv.w;
  #pragma unroll 4
  for (int k = 0; k < ID; ++k) {
    float4 wv = *(const float4*)(wptr + k * NHD);
    float4 a0 = *(const float4*)(&hs[k * 20 + r0]);
    float4 a1 = *(const float4*)(&hs[k * 20 + r0 + 4]);
    K1_FMA(a0.x, a0c) K1_FMA(a0.y, a1c) K1_FMA(a0.z, a2c) K1_FMA(a0.w, a3c)
    K1_FMA(a1.x, a4c) K1_FMA(a1.y, a5c) K1_FMA(a1.z, a6c) K1_FMA(a1.w, a7c)
  }
#undef K1_FMA
  {
    size_t off = ((((size_t)b * NH + head) * NA) + (n0 + r0)) * HD + d0;
    *(float4*)(hp + off) = a0c; off += HD;
    *(float4*)(hp + off) = a1c; off += HD;
    *(float4*)(hp + off) = a2c; off += HD;
    *(float4*)(hp + off) = a3c; off += HD;
    *(float4*)(hp + off) = a4c; off += HD;
    *(float4*)(hp + off) = a5c; off += HD;
    *(float4*)(hp + off) = a6c; off += HD;
    *(float4*)(hp + off) = a7c;
  }
  {
    float4 as4 = *(const float4*)(att + head * 128 + d0);
    float4 ad4 = *(const float4*)(att + head * 128 + 64 + d0);
#define DOT4(C, A) ((C).x*(A).x + (C).y*(A).y + (C).z*(A).z + (C).w*(A).w)
    float sp0 = DOT4(a0c, as4), tp0 = DOT4(a0c, ad4);
    float sp1 = DOT4(a1c, as4), tp1 = DOT4(a1c, ad4);
    float sp2 = DOT4(a2c, as4), tp2 = DOT4(a2c, ad4);
    float sp3 = DOT4(a3c, as4), tp3 = DOT4(a3c, ad4);
    float sp4 = DOT4(a4c, as4), tp4 = DOT4(a4c, ad4);
    float sp5 = DOT4(a5c, as4), tp5 = DOT4(a5c, ad4);
    float sp6 = DOT4(a6c, as4), tp6 = DOT4(a6c, ad4);
    float sp7 = DOT4(a7c, as4), tp7 = DOT4(a7c, ad4);
#undef DOT4
    #pragma unroll
    for (int m = 1; m < 16; m <<= 1) {
      sp0 += __shfl_xor(sp0, m, 64); tp0 += __shfl_xor(tp0, m, 64);
      sp1 += __shfl_xor(sp1, m, 64); tp1 += __shfl_xor(tp1, m, 64);
      sp2 += __shfl_xor(sp2, m, 64); tp2 += __shfl_xor(tp2, m, 64);
      sp3 += __shfl_xor(sp3, m, 64); tp3 += __shfl_xor(tp3, m, 64);
      sp4 += __shfl_xor(sp4, m, 64); tp4 += __shfl_xor(tp4, m, 64);
      sp5 += __shfl_xor(sp5, m, 64); tp5 += __shfl_xor(tp5, m, 64);
      sp6 += __shfl_xor(sp6, m, 64); tp6 += __shfl_xor(tp6, m, 64);
      sp7 += __shfl_xor(sp7, m, 64); tp7 += __shfl_xor(tp7, m, 64);
    }
    int g16 = lane & 15;
    int rsel = g16 & 7;
    float sv_ = rsel == 0 ? sp0 : rsel == 1 ? sp1 : rsel == 2 ? sp2 :
                rsel == 3 ? sp3 : rsel == 4 ? sp4 : rsel == 5 ? sp5 :
                rsel == 6 ? sp6 : sp7;
    float tv_ = rsel == 0 ? tp0 : rsel == 1 ? tp1 : rsel == 2 ? tp2 :
                rsel == 3 ? tp3 : rsel == 4 ? tp4 : rsel == 5 ? tp5 :
                rsel == 6 ? tp6 : tp7;
    size_t off = (((size_t)b * NH + head) * NA) + n0 + r0 + rsel;
    if (g16 < 8) s_out[off] = sv_;
    else         t_out[off] = tv_;
  }
}

// K2a: per-(b,h): hybrid bitonic sort of t (shfl for stride<64 -> ~12
// barriers not 45), chunk tables in LDS, then FULL-resolution suffix/prefix
// vector tables streamed to global (no indirection left for k2b), plus
// per-row {A,B,1/den,js}.
__global__ __launch_bounds__(512) void k2a_tables(
    const float* __restrict__ hp, const float* __restrict__ s_g,
    const float* __restrict__ t_g, float* __restrict__ sufPfull,
    float* __restrict__ preNfull, float4* __restrict__ rinfo_g) {
  __shared__ float tv[NA]; __shared__ int tpm[NA];
  __shared__ float wp[NA]; __shared__ float wn[NA];
  __shared__ float rawP[NC * 64]; __shared__ float rawN[NC * 64];
  __shared__ float sufP[(NC + 1) * 64]; __shared__ float preN[(NC + 1) * 64];
  __shared__ float zps[NA + 1]; __shared__ float znp[NA + 1];
  __shared__ float szP[NC]; __shared__ float szN[NC];
  __shared__ float sufZ[NC + 1]; __shared__ float preZ[NC + 1];
  __shared__ float smax8[8];

  int bh = blockIdx.x;
  int t = threadIdx.x;
  int lane = t & 63, w = t >> 6;
  const float* vbase = hp + (size_t)bh * NA * HD;

  // hybrid bitonic sort (value+index in regs)
  float v = t_g[(size_t)bh * NA + t];
  int idx = t;
  for (int size = 2; size <= NA; size <<= 1) {
    bool dirAsc = ((t & size) == 0);
    for (int stride = size >> 1; stride > 0; stride >>= 1) {
      float pv; int pi;
      if (stride >= 64) {
        tv[t] = v; tpm[t] = idx;
        __syncthreads();
        pv = tv[t ^ stride]; pi = tpm[t ^ stride];
        __syncthreads();
      } else {
        pv = __shfl_xor(v, stride, 64);
        pi = __shfl_xor(idx, stride, 64);
      }
      bool mn = (((t & stride) == 0) == dirAsc);
      bool sw = mn ? (pv < v) : (pv > v);
      if (sw) { v = pv; idx = pi; }
    }
  }
  tv[t] = v; tpm[t] = idx;
  __syncthreads();

  float cmax = fmaxf(tv[NA - 1], 0.f);
  wp[t] = __expf(tv[t] - cmax);
  wn[t] = __expf(NEG * tv[t] - cmax);
  float sval = s_g[(size_t)bh * NA + t];
  {
    float m = sval;
    #pragma unroll
    for (int d = 32; d; d >>= 1) m = fmaxf(m, __shfl_xor(m, d, 64));
    if (lane == 0) smax8[w] = m;
  }
  __syncthreads();
  float amax = fmaxf(fmaxf(fmaxf(smax8[0], smax8[1]), fmaxf(smax8[2], smax8[3])),
                     fmaxf(fmaxf(smax8[4], smax8[5]), fmaxf(smax8[6], smax8[7])));
  amax = fmaxf(amax, 0.f);

  // chunk vector sums over sorted order (coalesced V reads: lane = dim)
  {
    for (int cc = w; cc < NC; cc += 8) {
      float aP = 0.f, aN = 0.f;
      #pragma unroll
      for (int jj = 0; jj < CH; ++jj) {
        int j = cc * CH + jj;
        float vv = vbase[(size_t)tpm[j] * HD + lane];
        aP += wp[j] * vv;
        aN += wn[j] * vv;
      }
      rawP[cc * 64 + lane] = aP;
      rawN[cc * 64 + lane] = aN;
    }
  }
  __syncthreads();

  if (t < 64) {
    int d = t; float run = 0.f;
    sufP[NC * 64 + d] = 0.f;
    for (int cc = NC - 1; cc >= 0; --cc) { run += rawP[cc * 64 + d]; sufP[cc * 64 + d] = run; }
  } else if (t < 128) {
    int d = t - 64; float run = 0.f;
    for (int cc = 0; cc <= NC; ++cc) { preN[cc * 64 + d] = run; if (cc < NC) run += rawN[cc * 64 + d]; }
  } else if (t < 160) {
    int c = t - 128; float a = 0.f;
    for (int j = c * CH; j < c * CH + CH; ++j) a += wp[j];
    szP[c] = a;
  } else if (t < 192) {
    int c = t - 160; float a = 0.f;
    for (int j = c * CH; j < c * CH + CH; ++j) a += wn[j];
    szN[c] = a;
  }
  __syncthreads();

  if (t == 0) {
    float run = 0.f; sufZ[NC] = 0.f;
    for (int cc = NC - 1; cc >= 0; --cc) { run += szP[cc]; sufZ[cc] = run; }
  } else if (t == 1) {
    float run = 0.f;
    for (int cc = 0; cc <= NC; ++cc) { preZ[cc] = run; if (cc < NC) run += szN[cc]; }
  }
  __syncthreads();

  // full-resolution scalar tables for den
  {
    int ch = t >> 4;
    float a = 0.f;
    for (int k = t; k < ch * CH + CH; ++k) a += wp[k];
    zps[t] = a + sufZ[ch + 1];
    float b2 = 0.f;
    for (int k = ch * CH; k < t; ++k) b2 += wn[k];
    znp[t] = preZ[ch] + b2;
    if (t == 0) { zps[NA] = 0.f; znp[NA] = preZ[NC]; }
  }
  __syncthreads();

  // FULL-resolution vector tables -> global. Wave w owns sorted rows
  // [w*64, w*64+64); lane = dim -> 256B coalesced V reads + table writes.
  {
    float* sP = sufPfull + (size_t)bh * TROWS * 64;
    float* pN = preNfull + (size_t)bh * TROWS * 64;
    int jbase = w * 64;
    float run = sufP[(w * 4 + 4) * 64 + lane];   // chunk-suffix seed
    for (int jj = 63; jj >= 0; --jj) {
      int j = jbase + jj;
      float vv = vbase[(size_t)tpm[j] * HD + lane];
      run += wp[j] * vv;
      sP[(size_t)j * 64 + lane] = run;
    }
    float run2 = preN[(w * 4) * 64 + lane];      // chunk-prefix seed
    for (int jj = 0; jj < 64; ++jj) {
      int j = jbase + jj;
      pN[(size_t)j * 64 + lane] = run2;
      float vv = vbase[(size_t)tpm[j] * HD + lane];
      run2 += wn[j] * vv;
    }
    if (t < 64) {
      sP[(size_t)NA * 64 + t] = 0.f;
      pN[(size_t)NA * 64 + t] = preN[NC * 64 + t];
    }
  }

  // per-row info (thread t = original row t)
  {
    float A = __expf(sval - amax);
    float B = __expf(NEG * sval - amax);
    float key = -sval;
    int lo = 0, hi = NA;
    while (lo < hi) { int mid = (lo + hi) >> 1; if (tv[mid] < key) lo = mid + 1; else hi = mid; }
    int js = lo;
    float den = A * zps[js] + B * znp[js];
    float4 ri;
    ri.x = A; ri.y = B; ri.z = 1.f / den; ri.w = __int_as_float(js);
    rinfo_g[(size_t)bh * NA + t] = ri;
  }
}

// K2b: pure apply — no indirection, no LDS, no barriers. Thread = one output
// element. 2 coalesced loads + ELU + 1 coalesced store.
__global__ __launch_bounds__(256) void k2b_apply(
    const float* __restrict__ sufPfull, const float* __restrict__ preNfull,
    const float4* __restrict__ rinfo_g, float* __restrict__ out) {
  int blk = blockIdx.x;           // 32768 blocks: bh = blk>>7, 4 rows/block
  int bh = blk >> 7;
  int row = (blk & 127) * 4 + (threadIdx.x >> 6);
  int lane = threadIdx.x & 63;
  float4 ri = rinfo_g[(size_t)bh * NA + row];
  int js = __float_as_int(ri.w);
  size_t tb = ((size_t)bh * TROWS + js) * 64 + lane;
  float x = (ri.x * sufPfull[tb] + ri.y * preNfull[tb]) * ri.z;
  out[(((size_t)bh * NA) + row) * 64 + lane] = x > 0.f ? x : __expf(x) - 1.f;
}

// Fallback (R4-proven combined k2) if ws_size can't hold the full tables.
__global__ __launch_bounds__(512) void k2_fallback(
    const float* __restrict__ hp, const float* __restrict__ s_g,
    const float* __restrict__ t_g, float* __restrict__ out) {
  __shared__ float tv[NA]; __shared__ int tpm[NA];
  __shared__ float sv[NA]; __shared__ int spm[NA];
  __shared__ float wp[NA]; __shared__ float wn[NA];
  __shared__ float rawP[NC * 64]; __shared__ float rawN[NC * 64];
  __shared__ float sufP[(NC + 1) * 64]; __shared__ float preN[(NC + 1) * 64];
  __shared__ float zps[NA + 1]; __shared__ float znp[NA + 1];
  __shared__ float szP[NC]; __shared__ float szN[NC];
  __shared__ float sufZ[NC + 1]; __shared__ float preZ[NC + 1];
  int bh = blockIdx.x;
  int t = threadIdx.x;
  const float* vbase = hp + (size_t)bh * NA * HD;
  tv[t] = t_g[(size_t)bh * NA + t]; tpm[t] = t;
  sv[t] = s_g[(size_t)bh * NA + t]; spm[t] = t;
  __syncthreads();
  for (int size = 2; size <= NA; size <<= 1) {
    for (int stride = size >> 1; stride > 0; stride >>= 1) {
      int i = t, j = i ^ stride;
      if (j > i) {
        bool up = ((i & size) == 0);
        float a = tv[i], b = tv[j];
        if (up ? (a > b) : (a < b)) {
          tv[i] = b; tv[j] = a;
          int x = tpm[i]; tpm[i] = tpm[j]; tpm[j] = x;
        }
        float c = sv[i], d = sv[j];
        if (up ? (c > d) : (c < d)) {
          sv[i] = d; sv[j] = c;
          int x = spm[i]; spm[i] = spm[j]; spm[j] = x;
        }
      }
      __syncthreads();
    }
  }
  float cmax = fmaxf(tv[NA - 1], 0.f);
  float amax = fmaxf(sv[NA - 1], 0.f);
  wp[t] = __expf(tv[t] - cmax);
  wn[t] = __expf(NEG * tv[t] - cmax);
  __syncthreads();
  {
    int d = t & 63, w8 = t >> 6;
    for (int cc = w8; cc < NC; cc += 8) {
      float aP = 0.f, aN = 0.f;
      #pragma unroll
      for (int jj = 0; jj < CH; ++jj) {
        int j = cc * CH + jj;
        float vv = vbase[(size_t)tpm[j] * HD + d];
        aP += wp[j] * vv;
        aN += wn[j] * vv;
      }
      rawP[cc * 64 + d] = aP;
      rawN[cc * 64 + d] = aN;
    }
  }
  __syncthreads();
  if (t < 64) {
    int d = t; float run = 0.f;
    sufP[NC * 64 + d] = 0.f;
    for (int cc = NC - 1; cc >= 0; --cc) { run += rawP[cc * 64 + d]; sufP[cc * 64 + d] = run; }
  } else if (t < 128) {
    int d = t - 64; float run = 0.f;
    for (int cc = 0; cc <= NC; ++cc) { preN[cc * 64 + d] = run; if (cc < NC) run += rawN[cc * 64 + d]; }
  } else if (t < 160) {
    int c = t - 128; float a = 0.f;
    for (int j = c * CH; j < c * CH + CH; ++j) a += wp[j];
    szP[c] = a;
  } else if (t < 192) {
    int c = t - 160; float a = 0.f;
    for (int j = c * CH; j < c * CH + CH; ++j) a += wn[j];
    szN[c] = a;
  }
  __syncthreads();
  if (t == 0) {
    float run = 0.f; sufZ[NC] = 0.f;
    for (int cc = NC - 1; cc >= 0; --cc) { run += szP[cc]; sufZ[cc] = run; }
  } else if (t == 1) {
    float run = 0.f;
    for (int cc = 0; cc <= NC; ++cc) { preZ[cc] = run; if (cc < NC) run += szN[cc]; }
  }
  __syncthreads();
  {
    int ch = t >> 4;
    float a = 0.f;
    for (int k = t; k < ch * CH + CH; ++k) a += wp[k];
    zps[t] = a + sufZ[ch + 1];
    float b2 = 0.f;
    for (int k = ch * CH; k < t; ++k) b2 += wn[k];
    znp[t] = preZ[ch] + b2;
    if (t == 0) { zps[NA] = 0.f; znp[NA] = preZ[NC]; }
  }
  __syncthreads();
  {
    float sval = sv[t];
    int row = spm[t];
    float A = __expf(sval - amax);
    float B = __expf(NEG * sval - amax);
    float key = -sval;
    int lo = 0, hi = NA;
    while (lo < hi) { int mid = (lo + hi) >> 1; if (tv[mid] < key) lo = mid + 1; else hi = mid; }
    int js = lo;
    int cs = js >> 4; if (cs > NC - 1) cs = NC - 1;
    float den = A * zps[js] + B * znp[js];
    float inv = 1.f / den;
    const float* sp_ = &sufP[(cs + 1) * 64];
    const float* pn_ = &preN[cs * 64];
    float* ob = out + ((size_t)bh * NA + row) * HD;
#define INIT4(P) { float4 aa = *(const float4*)(sp_ + (P));                   \
                   float4 bb = *(const float4*)(pn_ + (P));                   \
                   nn.x = A*aa.x + B*bb.x; nn.y = A*aa.y + B*bb.y;            \
                   nn.z = A*aa.z + B*bb.z; nn.w = A*aa.w + B*bb.w; }
#define LD_FMA(NN, P) { float4 vv = *(const float4*)(vrow + (P));             \
                        NN.x += coef*vv.x; NN.y += coef*vv.y;                 \
                        NN.z += coef*vv.z; NN.w += coef*vv.w; }
#define ELU_ST(NN, P) { float4 ov;                                            \
                        float x0 = NN.x*inv; ov.x = x0>0.f?x0:__expf(x0)-1.f; \
                        float x1 = NN.y*inv; ov.y = x1>0.f?x1:__expf(x1)-1.f; \
                        float x2 = NN.z*inv; ov.z = x2>0.f?x2:__expf(x2)-1.f; \
                        float x3 = NN.w*inv; ov.w = x3>0.f?x3:__expf(x3)-1.f; \
                        *(float4*)(ob + (P)) = ov; }
    #pragma unroll
    for (int half = 0; half < 2; ++half) {
      int ho = half * 32;
      float4 n0, n1, n2, n3, n4, n5, n6, n7;
      { float4 nn; INIT4(ho +  0) n0 = nn; INIT4(ho +  4) n1 = nn;
                   INIT4(ho +  8) n2 = nn; INIT4(ho + 12) n3 = nn;
                   INIT4(ho + 16) n4 = nn; INIT4(ho + 20) n5 = nn;
                   INIT4(ho + 24) n6 = nn; INIT4(ho + 28) n7 = nn; }
      #pragma unroll 2
      for (int jj = 0; jj < CH; ++jj) {
        int j = cs * CH + jj;
        float coef = (j >= js) ? A * wp[j] : B * wn[j];
        const float* vrow = vbase + (size_t)tpm[j] * HD + ho;
        LD_FMA(n0,  0) LD_FMA(n1,  4) LD_FMA(n2,  8) LD_FMA(n3, 12)
        LD_FMA(n4, 16) LD_FMA(n5, 20) LD_FMA(n6, 24) LD_FMA(n7, 28)
      }
      ELU_ST(n0, ho +  0) ELU_ST(n1, ho +  4) ELU_ST(n2, ho +  8)
      ELU_ST(n3, ho + 12) ELU_ST(n4, ho + 16) ELU_ST(n5, ho + 20)
      ELU_ST(n6, ho + 24) ELU_ST(n7, ho + 28)
    }
#undef INIT4
#undef LD_FMA
#undef ELU_ST
  }
}

extern "C" void kernel_launch(void* const* d_in, const int* in_sizes, int n_in,
                              void* d_out, int out_size, void* d_ws, size_t ws_size,
                              hipStream_t stream) {
  const float* h  = (const float*)d_in[0];
  const float* W  = (const float*)d_in[1];
  const float* att = (const float*)d_in[2];
  float* out = (float*)d_out;
  // ws floats: hp 8.39M | s .131M | t .131M | sufPfull 8.40M | preNfull 8.40M
  // | rinfo (float4) .524M*4B... total ~104 MB. Fallback if ws too small.
  float* hp    = (float*)d_ws;
  float* s_arr = hp + (size_t)BS * NH * NA * HD;
  float* t_arr = s_arr + (size_t)BS * NH * NA;
  float* sufPf = t_arr + (size_t)BS * NH * NA;
  float* preNf = sufPf + (size_t)BS * NH * TROWS * 64;
  float* rinfo = preNf + (size_t)BS * NH * TROWS * 64;
  size_t need_floats = (size_t)BS * NH * NA * HD + 2 * (size_t)BS * NH * NA +
                       2 * (size_t)BS * NH * TROWS * 64 + (size_t)BS * NH * NA * 4;
  size_t need = need_floats * sizeof(float);

  k1_gemm<<<dim3(1024), dim3(256), 0, stream>>>(h, W, att, hp, s_arr, t_arr);
  if (ws_size >= need) {
    k2a_tables<<<dim3(256),   dim3(512), 0, stream>>>(hp, s_arr, t_arr, sufPf,
                                                      preNf, (float4*)rinfo);
    k2b_apply <<<dim3(32768), dim3(256), 0, stream>>>(sufPf, preNf,
                                                      (float4*)rinfo, out);
  } else {
    k2_fallback<<<dim3(256), dim3(512), 0, stream>>>(hp, s_arr, t_arr, out);
  }
}

// Round 7
// 148.391 us; speedup vs baseline: 1.3326x; 1.0438x over previous
//
#include <hip/hip_runtime.h>

#define BS 32
#define NA 512
#define ID 128
#define NH 8
#define HD 64
#define NHD 512   // NH*HD
#define NEG 0.2f
#define NC 32
#define CH 16
#define TROWS (NA + 1)   // 513 table rows per bh (row NA handles js==512)

// K1: h_prime = h @ W (fp32). Block = 16 rows x 512 cols, 4 waves: wave w has
// rows (w>>1)*8..+7 (WAVE-UNIFORM -> A via s_load, zero LDS/DS traffic; R6
// showed the DS pipe cost ~20us) and cols (w&1)*256 + 4*lane (dense 1KB W
// loads). readfirstlane forces the compiler's uniformity analysis to put A
// addresses in SGPRs.
__global__ __launch_bounds__(256) void k1_gemm(
    const float* __restrict__ h, const float* __restrict__ W,
    const float* __restrict__ att, float* __restrict__ hp,
    float* __restrict__ s_out, float* __restrict__ t_out) {
  int blk = blockIdx.x;
  int b = blk >> 5;
  int n0 = (blk & 31) * 16;
  int t = threadIdx.x;
  int lane = t & 63, w = t >> 6;
  int r0 = __builtin_amdgcn_readfirstlane((w >> 1) * 8);   // 0 or 8
  int chalf = __builtin_amdgcn_readfirstlane(w & 1);
  int col = chalf * 256 + lane * 4;
  int head = col >> 6;
  int d0 = col & 63;
  const float* arow = h + ((size_t)b * NA + n0 + r0) * ID;  // uniform base
  const float* wptr = W + col;

  float4 a0c = {0,0,0,0}, a1c = {0,0,0,0}, a2c = {0,0,0,0}, a3c = {0,0,0,0};
  float4 a4c = {0,0,0,0}, a5c = {0,0,0,0}, a6c = {0,0,0,0}, a7c = {0,0,0,0};

#define K1_ROW(I, C, KK)                                                      \
  { float a_ = arow[(I) * ID + kc + (KK)];                                    \
    C.x += a_ * wv.x; C.y += a_ * wv.y; C.z += a_ * wv.z; C.w += a_ * wv.w; }
  #pragma unroll 1
  for (int kc = 0; kc < ID; kc += 8) {
    #pragma unroll
    for (int kk = 0; kk < 8; ++kk) {
      float4 wv = *(const float4*)(wptr + (size_t)(kc + kk) * NHD);
      K1_ROW(0, a0c, kk) K1_ROW(1, a1c, kk) K1_ROW(2, a2c, kk)
      K1_ROW(3, a3c, kk) K1_ROW(4, a4c, kk) K1_ROW(5, a5c, kk)
      K1_ROW(6, a6c, kk) K1_ROW(7, a7c, kk)
    }
  }
#undef K1_ROW
  {
    size_t off = ((((size_t)b * NH + head) * NA) + (n0 + r0)) * HD + d0;
    *(float4*)(hp + off) = a0c; off += HD;
    *(float4*)(hp + off) = a1c; off += HD;
    *(float4*)(hp + off) = a2c; off += HD;
    *(float4*)(hp + off) = a3c; off += HD;
    *(float4*)(hp + off) = a4c; off += HD;
    *(float4*)(hp + off) = a5c; off += HD;
    *(float4*)(hp + off) = a6c; off += HD;
    *(float4*)(hp + off) = a7c;
  }
  {
    float4 as4 = *(const float4*)(att + head * 128 + d0);
    float4 ad4 = *(const float4*)(att + head * 128 + 64 + d0);
#define DOT4(C, A) ((C).x*(A).x + (C).y*(A).y + (C).z*(A).z + (C).w*(A).w)
    float sp0 = DOT4(a0c, as4), tp0 = DOT4(a0c, ad4);
    float sp1 = DOT4(a1c, as4), tp1 = DOT4(a1c, ad4);
    float sp2 = DOT4(a2c, as4), tp2 = DOT4(a2c, ad4);
    float sp3 = DOT4(a3c, as4), tp3 = DOT4(a3c, ad4);
    float sp4 = DOT4(a4c, as4), tp4 = DOT4(a4c, ad4);
    float sp5 = DOT4(a5c, as4), tp5 = DOT4(a5c, ad4);
    float sp6 = DOT4(a6c, as4), tp6 = DOT4(a6c, ad4);
    float sp7 = DOT4(a7c, as4), tp7 = DOT4(a7c, ad4);
#undef DOT4
    #pragma unroll
    for (int m = 1; m < 16; m <<= 1) {
      sp0 += __shfl_xor(sp0, m, 64); tp0 += __shfl_xor(tp0, m, 64);
      sp1 += __shfl_xor(sp1, m, 64); tp1 += __shfl_xor(tp1, m, 64);
      sp2 += __shfl_xor(sp2, m, 64); tp2 += __shfl_xor(tp2, m, 64);
      sp3 += __shfl_xor(sp3, m, 64); tp3 += __shfl_xor(tp3, m, 64);
      sp4 += __shfl_xor(sp4, m, 64); tp4 += __shfl_xor(tp4, m, 64);
      sp5 += __shfl_xor(sp5, m, 64); tp5 += __shfl_xor(tp5, m, 64);
      sp6 += __shfl_xor(sp6, m, 64); tp6 += __shfl_xor(tp6, m, 64);
      sp7 += __shfl_xor(sp7, m, 64); tp7 += __shfl_xor(tp7, m, 64);
    }
    int g16 = lane & 15;
    int rsel = g16 & 7;
    float sv_ = rsel == 0 ? sp0 : rsel == 1 ? sp1 : rsel == 2 ? sp2 :
                rsel == 3 ? sp3 : rsel == 4 ? sp4 : rsel == 5 ? sp5 :
                rsel == 6 ? sp6 : sp7;
    float tv_ = rsel == 0 ? tp0 : rsel == 1 ? tp1 : rsel == 2 ? tp2 :
                rsel == 3 ? tp3 : rsel == 4 ? tp4 : rsel == 5 ? tp5 :
                rsel == 6 ? tp6 : tp7;
    size_t off = (((size_t)b * NH + head) * NA) + n0 + r0 + rsel;
    if (g16 < 8) s_out[off] = sv_;
    else         t_out[off] = tv_;
  }
}

// K2a: per-(b,h): hybrid bitonic sort of t (shfl for stride<64), chunk tables
// in LDS, then FULL-resolution suffix/prefix vector tables streamed to global,
// plus per-row {A,B,1/den,js}.
__global__ __launch_bounds__(512) void k2a_tables(
    const float* __restrict__ hp, const float* __restrict__ s_g,
    const float* __restrict__ t_g, float* __restrict__ sufPfull,
    float* __restrict__ preNfull, float4* __restrict__ rinfo_g) {
  __shared__ float tv[NA]; __shared__ int tpm[NA];
  __shared__ float wp[NA]; __shared__ float wn[NA];
  __shared__ float rawP[NC * 64]; __shared__ float rawN[NC * 64];
  __shared__ float sufP[(NC + 1) * 64]; __shared__ float preN[(NC + 1) * 64];
  __shared__ float zps[NA + 1]; __shared__ float znp[NA + 1];
  __shared__ float szP[NC]; __shared__ float szN[NC];
  __shared__ float sufZ[NC + 1]; __shared__ float preZ[NC + 1];
  __shared__ float smax8[8];

  int bh = blockIdx.x;
  int t = threadIdx.x;
  int lane = t & 63, w = t >> 6;
  const float* vbase = hp + (size_t)bh * NA * HD;

  // hybrid bitonic sort (value+index in regs)
  float v = t_g[(size_t)bh * NA + t];
  int idx = t;
  for (int size = 2; size <= NA; size <<= 1) {
    bool dirAsc = ((t & size) == 0);
    for (int stride = size >> 1; stride > 0; stride >>= 1) {
      float pv; int pi;
      if (stride >= 64) {
        tv[t] = v; tpm[t] = idx;
        __syncthreads();
        pv = tv[t ^ stride]; pi = tpm[t ^ stride];
        __syncthreads();
      } else {
        pv = __shfl_xor(v, stride, 64);
        pi = __shfl_xor(idx, stride, 64);
      }
      bool mn = (((t & stride) == 0) == dirAsc);
      bool sw = mn ? (pv < v) : (pv > v);
      if (sw) { v = pv; idx = pi; }
    }
  }
  tv[t] = v; tpm[t] = idx;
  __syncthreads();

  float cmax = fmaxf(tv[NA - 1], 0.f);
  wp[t] = __expf(tv[t] - cmax);
  wn[t] = __expf(NEG * tv[t] - cmax);
  float sval = s_g[(size_t)bh * NA + t];
  {
    float m = sval;
    #pragma unroll
    for (int d = 32; d; d >>= 1) m = fmaxf(m, __shfl_xor(m, d, 64));
    if (lane == 0) smax8[w] = m;
  }
  __syncthreads();
  float amax = fmaxf(fmaxf(fmaxf(smax8[0], smax8[1]), fmaxf(smax8[2], smax8[3])),
                     fmaxf(fmaxf(smax8[4], smax8[5]), fmaxf(smax8[6], smax8[7])));
  amax = fmaxf(amax, 0.f);

  // chunk vector sums over sorted order (coalesced V reads: lane = dim)
  {
    for (int cc = w; cc < NC; cc += 8) {
      float aP = 0.f, aN = 0.f;
      #pragma unroll
      for (int jj = 0; jj < CH; ++jj) {
        int j = cc * CH + jj;
        float vv = vbase[(size_t)tpm[j] * HD + lane];
        aP += wp[j] * vv;
        aN += wn[j] * vv;
      }
      rawP[cc * 64 + lane] = aP;
      rawN[cc * 64 + lane] = aN;
    }
  }
  __syncthreads();

  if (t < 64) {
    int d = t; float run = 0.f;
    sufP[NC * 64 + d] = 0.f;
    for (int cc = NC - 1; cc >= 0; --cc) { run += rawP[cc * 64 + d]; sufP[cc * 64 + d] = run; }
  } else if (t < 128) {
    int d = t - 64; float run = 0.f;
    for (int cc = 0; cc <= NC; ++cc) { preN[cc * 64 + d] = run; if (cc < NC) run += rawN[cc * 64 + d]; }
  } else if (t < 160) {
    int c = t - 128; float a = 0.f;
    for (int j = c * CH; j < c * CH + CH; ++j) a += wp[j];
    szP[c] = a;
  } else if (t < 192) {
    int c = t - 160; float a = 0.f;
    for (int j = c * CH; j < c * CH + CH; ++j) a += wn[j];
    szN[c] = a;
  }
  __syncthreads();

  if (t == 0) {
    float run = 0.f; sufZ[NC] = 0.f;
    for (int cc = NC - 1; cc >= 0; --cc) { run += szP[cc]; sufZ[cc] = run; }
  } else if (t == 1) {
    float run = 0.f;
    for (int cc = 0; cc <= NC; ++cc) { preZ[cc] = run; if (cc < NC) run += szN[cc]; }
  }
  __syncthreads();

  // full-resolution scalar tables for den
  {
    int ch = t >> 4;
    float a = 0.f;
    for (int k = t; k < ch * CH + CH; ++k) a += wp[k];
    zps[t] = a + sufZ[ch + 1];
    float b2 = 0.f;
    for (int k = ch * CH; k < t; ++k) b2 += wn[k];
    znp[t] = preZ[ch] + b2;
    if (t == 0) { zps[NA] = 0.f; znp[NA] = preZ[NC]; }
  }
  __syncthreads();

  // FULL-resolution vector tables -> global. Wave w owns sorted rows
  // [w*64, w*64+64); lane = dim -> 256B coalesced V reads + table writes.
  {
    float* sP = sufPfull + (size_t)bh * TROWS * 64;
    float* pN = preNfull + (size_t)bh * TROWS * 64;
    int jbase = w * 64;
    float run = sufP[(w * 4 + 4) * 64 + lane];   // chunk-suffix seed
    for (int jj = 63; jj >= 0; --jj) {
      int j = jbase + jj;
      float vv = vbase[(size_t)tpm[j] * HD + lane];
      run += wp[j] * vv;
      sP[(size_t)j * 64 + lane] = run;
    }
    float run2 = preN[(w * 4) * 64 + lane];      // chunk-prefix seed
    for (int jj = 0; jj < 64; ++jj) {
      int j = jbase + jj;
      pN[(size_t)j * 64 + lane] = run2;
      float vv = vbase[(size_t)tpm[j] * HD + lane];
      run2 += wn[j] * vv;
    }
    if (t < 64) {
      sP[(size_t)NA * 64 + t] = 0.f;
      pN[(size_t)NA * 64 + t] = preN[NC * 64 + t];
    }
  }

  // per-row info (thread t = original row t)
  {
    float A = __expf(sval - amax);
    float B = __expf(NEG * sval - amax);
    float key = -sval;
    int lo = 0, hi = NA;
    while (lo < hi) { int mid = (lo + hi) >> 1; if (tv[mid] < key) lo = mid + 1; else hi = mid; }
    int js = lo;
    float den = A * zps[js] + B * znp[js];
    float4 ri;
    ri.x = A; ri.y = B; ri.z = 1.f / den; ri.w = __int_as_float(js);
    rinfo_g[(size_t)bh * NA + t] = ri;
  }
}

// K2b: pure apply — no indirection, no LDS, no barriers.
__global__ __launch_bounds__(256) void k2b_apply(
    const float* __restrict__ sufPfull, const float* __restrict__ preNfull,
    const float4* __restrict__ rinfo_g, float* __restrict__ out) {
  int blk = blockIdx.x;           // 32768 blocks: bh = blk>>7, 4 rows/block
  int bh = blk >> 7;
  int row = (blk & 127) * 4 + (threadIdx.x >> 6);
  int lane = threadIdx.x & 63;
  float4 ri = rinfo_g[(size_t)bh * NA + row];
  int js = __float_as_int(ri.w);
  size_t tb = ((size_t)bh * TROWS + js) * 64 + lane;
  float x = (ri.x * sufPfull[tb] + ri.y * preNfull[tb]) * ri.z;
  out[(((size_t)bh * NA) + row) * 64 + lane] = x > 0.f ? x : __expf(x) - 1.f;
}

// Fallback (R4-proven combined k2) if ws_size can't hold the full tables.
__global__ __launch_bounds__(512) void k2_fallback(
    const float* __restrict__ hp, const float* __restrict__ s_g,
    const float* __restrict__ t_g, float* __restrict__ out) {
  __shared__ float tv[NA]; __shared__ int tpm[NA];
  __shared__ float sv[NA]; __shared__ int spm[NA];
  __shared__ float wp[NA]; __shared__ float wn[NA];
  __shared__ float rawP[NC * 64]; __shared__ float rawN[NC * 64];
  __shared__ float sufP[(NC + 1) * 64]; __shared__ float preN[(NC + 1) * 64];
  __shared__ float zps[NA + 1]; __shared__ float znp[NA + 1];
  __shared__ float szP[NC]; __shared__ float szN[NC];
  __shared__ float sufZ[NC + 1]; __shared__ float preZ[NC + 1];
  int bh = blockIdx.x;
  int t = threadIdx.x;
  const float* vbase = hp + (size_t)bh * NA * HD;
  tv[t] = t_g[(size_t)bh * NA + t]; tpm[t] = t;
  sv[t] = s_g[(size_t)bh * NA + t]; spm[t] = t;
  __syncthreads();
  for (int size = 2; size <= NA; size <<= 1) {
    for (int stride = size >> 1; stride > 0; stride >>= 1) {
      int i = t, j = i ^ stride;
      if (j > i) {
        bool up = ((i & size) == 0);
        float a = tv[i], b = tv[j];
        if (up ? (a > b) : (a < b)) {
          tv[i] = b; tv[j] = a;
          int x = tpm[i]; tpm[i] = tpm[j]; tpm[j] = x;
        }
        float c = sv[i], d = sv[j];
        if (up ? (c > d) : (c < d)) {
          sv[i] = d; sv[j] = c;
          int x = spm[i]; spm[i] = spm[j]; spm[j] = x;
        }
      }
      __syncthreads();
    }
  }
  float cmax = fmaxf(tv[NA - 1], 0.f);
  float amax = fmaxf(sv[NA - 1], 0.f);
  wp[t] = __expf(tv[t] - cmax);
  wn[t] = __expf(NEG * tv[t] - cmax);
  __syncthreads();
  {
    int d = t & 63, w8 = t >> 6;
    for (int cc = w8; cc < NC; cc += 8) {
      float aP = 0.f, aN = 0.f;
      #pragma unroll
      for (int jj = 0; jj < CH; ++jj) {
        int j = cc * CH + jj;
        float vv = vbase[(size_t)tpm[j] * HD + d];
        aP += wp[j] * vv;
        aN += wn[j] * vv;
      }
      rawP[cc * 64 + d] = aP;
      rawN[cc * 64 + d] = aN;
    }
  }
  __syncthreads();
  if (t < 64) {
    int d = t; float run = 0.f;
    sufP[NC * 64 + d] = 0.f;
    for (int cc = NC - 1; cc >= 0; --cc) { run += rawP[cc * 64 + d]; sufP[cc * 64 + d] = run; }
  } else if (t < 128) {
    int d = t - 64; float run = 0.f;
    for (int cc = 0; cc <= NC; ++cc) { preN[cc * 64 + d] = run; if (cc < NC) run += rawN[cc * 64 + d]; }
  } else if (t < 160) {
    int c = t - 128; float a = 0.f;
    for (int j = c * CH; j < c * CH + CH; ++j) a += wp[j];
    szP[c] = a;
  } else if (t < 192) {
    int c = t - 160; float a = 0.f;
    for (int j = c * CH; j < c * CH + CH; ++j) a += wn[j];
    szN[c] = a;
  }
  __syncthreads();
  if (t == 0) {
    float run = 0.f; sufZ[NC] = 0.f;
    for (int cc = NC - 1; cc >= 0; --cc) { run += szP[cc]; sufZ[cc] = run; }
  } else if (t == 1) {
    float run = 0.f;
    for (int cc = 0; cc <= NC; ++cc) { preZ[cc] = run; if (cc < NC) run += szN[cc]; }
  }
  __syncthreads();
  {
    int ch = t >> 4;
    float a = 0.f;
    for (int k = t; k < ch * CH + CH; ++k) a += wp[k];
    zps[t] = a + sufZ[ch + 1];
    float b2 = 0.f;
    for (int k = ch * CH; k < t; ++k) b2 += wn[k];
    znp[t] = preZ[ch] + b2;
    if (t == 0) { zps[NA] = 0.f; znp[NA] = preZ[NC]; }
  }
  __syncthreads();
  {
    float sval = sv[t];
    int row = spm[t];
    float A = __expf(sval - amax);
    float B = __expf(NEG * sval - amax);
    float key = -sval;
    int lo = 0, hi = NA;
    while (lo < hi) { int mid = (lo + hi) >> 1; if (tv[mid] < key) lo = mid + 1; else hi = mid; }
    int js = lo;
    int cs = js >> 4; if (cs > NC - 1) cs = NC - 1;
    float den = A * zps[js] + B * znp[js];
    float inv = 1.f / den;
    const float* sp_ = &sufP[(cs + 1) * 64];
    const float* pn_ = &preN[cs * 64];
    float* ob = out + ((size_t)bh * NA + row) * HD;
#define INIT4(P) { float4 aa = *(const float4*)(sp_ + (P));                   \
                   float4 bb = *(const float4*)(pn_ + (P));                   \
                   nn.x = A*aa.x + B*bb.x; nn.y = A*aa.y + B*bb.y;            \
                   nn.z = A*aa.z + B*bb.z; nn.w = A*aa.w + B*bb.w; }
#define LD_FMA(NN, P) { float4 vv = *(const float4*)(vrow + (P));             \
                        NN.x += coef*vv.x; NN.y += coef*vv.y;                 \
                        NN.z += coef*vv.z; NN.w += coef*vv.w; }
#define ELU_ST(NN, P) { float4 ov;                                            \
                        float x0 = NN.x*inv; ov.x = x0>0.f?x0:__expf(x0)-1.f; \
                        float x1 = NN.y*inv; ov.y = x1>0.f?x1:__expf(x1)-1.f; \
                        float x2 = NN.z*inv; ov.z = x2>0.f?x2:__expf(x2)-1.f; \
                        float x3 = NN.w*inv; ov.w = x3>0.f?x3:__expf(x3)-1.f; \
                        *(float4*)(ob + (P)) = ov; }
    #pragma unroll
    for (int half = 0; half < 2; ++half) {
      int ho = half * 32;
      float4 n0, n1, n2, n3, n4, n5, n6, n7;
      { float4 nn; INIT4(ho +  0) n0 = nn; INIT4(ho +  4) n1 = nn;
                   INIT4(ho +  8) n2 = nn; INIT4(ho + 12) n3 = nn;
                   INIT4(ho + 16) n4 = nn; INIT4(ho + 20) n5 = nn;
                   INIT4(ho + 24) n6 = nn; INIT4(ho + 28) n7 = nn; }
      #pragma unroll 2
      for (int jj = 0; jj < CH; ++jj) {
        int j = cs * CH + jj;
        float coef = (j >= js) ? A * wp[j] : B * wn[j];
        const float* vrow = vbase + (size_t)tpm[j] * HD + ho;
        LD_FMA(n0,  0) LD_FMA(n1,  4) LD_FMA(n2,  8) LD_FMA(n3, 12)
        LD_FMA(n4, 16) LD_FMA(n5, 20) LD_FMA(n6, 24) LD_FMA(n7, 28)
      }
      ELU_ST(n0, ho +  0) ELU_ST(n1, ho +  4) ELU_ST(n2, ho +  8)
      ELU_ST(n3, ho + 12) ELU_ST(n4, ho + 16) ELU_ST(n5, ho + 20)
      ELU_ST(n6, ho + 24) ELU_ST(n7, ho + 28)
    }
#undef INIT4
#undef LD_FMA
#undef ELU_ST
  }
}

extern "C" void kernel_launch(void* const* d_in, const int* in_sizes, int n_in,
                              void* d_out, int out_size, void* d_ws, size_t ws_size,
                              hipStream_t stream) {
  const float* h  = (const float*)d_in[0];
  const float* W  = (const float*)d_in[1];
  const float* att = (const float*)d_in[2];
  float* out = (float*)d_out;
  float* hp    = (float*)d_ws;
  float* s_arr = hp + (size_t)BS * NH * NA * HD;
  float* t_arr = s_arr + (size_t)BS * NH * NA;
  float* sufPf = t_arr + (size_t)BS * NH * NA;
  float* preNf = sufPf + (size_t)BS * NH * TROWS * 64;
  float* rinfo = preNf + (size_t)BS * NH * TROWS * 64;
  size_t need_floats = (size_t)BS * NH * NA * HD + 2 * (size_t)BS * NH * NA +
                       2 * (size_t)BS * NH * TROWS * 64 + (size_t)BS * NH * NA * 4;
  size_t need = need_floats * sizeof(float);

  k1_gemm<<<dim3(1024), dim3(256), 0, stream>>>(h, W, att, hp, s_arr, t_arr);
  if (ws_size >= need) {
    k2a_tables<<<dim3(256),   dim3(512), 0, stream>>>(hp, s_arr, t_arr, sufPf,
                                                      preNf, (float4*)rinfo);
    k2b_apply <<<dim3(32768), dim3(256), 0, stream>>>(sufPf, preNf,
                                                      (float4*)rinfo, out);
  } else {
    k2_fallback<<<dim3(256), dim3(512), 0, stream>>>(hp, s_arr, t_arr, out);
  }
}